// Round 2
// baseline (334.151 us; speedup 1.0000x reference)
//
#include <hip/hip_runtime.h>

#define B_   32
#define S_   2048
#define D_   512
#define H_   32
#define BS_  (B_*S_)
#define INV_SCALE 0.17677669529663689f   // 1/sqrt(32)

// workspace layout (float offsets) — total 81920 floats = 320 KB
#define PT_OFF    0                       // [32][512] transposed projector (16384)
#define V_OFF     16384                   // [B][S] scores -> coefficients in place (65536)

__device__ __forceinline__ float sigmoidf_(float x) {
    return 1.0f / (1.0f + __expf(-x));
}

// ---------------- transpose projector: PT[j][d] = P[d][j] ----------------
__global__ void kTranspose(const float* __restrict__ P, float* __restrict__ PT) {
    int o = blockIdx.x * 256 + threadIdx.x;      // 16384 total
    int j = o >> 9, d = o & 511;
    PT[o] = P[d * H_ + j];
}

// ---------------- scores: v[b,s] for 128 rows per block ----------------
__global__ __launch_bounds__(256) void kScores(
        const float* __restrict__ inp, const int* __restrict__ mask,
        const float* __restrict__ PT, const float* __restrict__ hd,
        const float* __restrict__ ev, float* __restrict__ v) {
    __shared__ float w0[128 * 32];
    __shared__ float w1[128 * 33];   // +1 pad: evaluator dot is conflict-free

    const int tid = threadIdx.x;
    const int cg  = tid & 7;          // col group: cols cg*4 .. cg*4+3
    const int rg  = tid >> 3;         // row group: rows rg*4 .. rg*4+3
    const int rowBase = blockIdx.x * 128;

    float mr[4];
    const float4* xp[4];
    #pragma unroll
    for (int r = 0; r < 4; ++r) {
        int row = rowBase + rg * 4 + r;
        mr[r] = (mask[row] != 0) ? 1.0f : 0.0f;
        xp[r] = (const float4*)(inp + (size_t)row * D_);
    }
    const float4* pp[4];
    #pragma unroll
    for (int j = 0; j < 4; ++j)
        pp[j] = (const float4*)(PT + (size_t)(cg * 4 + j) * D_);

    float4 acc[4][4];
    #pragma unroll
    for (int r = 0; r < 4; ++r)
        #pragma unroll
        for (int j = 0; j < 4; ++j)
            acc[r][j] = make_float4(0.f, 0.f, 0.f, 0.f);

    #pragma unroll 4
    for (int d4 = 0; d4 < 128; ++d4) {
        float4 xv[4], pv[4];
        #pragma unroll
        for (int r = 0; r < 4; ++r) xv[r] = xp[r][d4];
        #pragma unroll
        for (int j = 0; j < 4; ++j) pv[j] = pp[j][d4];
        #pragma unroll
        for (int r = 0; r < 4; ++r)
            #pragma unroll
            for (int j = 0; j < 4; ++j) {
                acc[r][j].x = fmaf(xv[r].x, pv[j].x, acc[r][j].x);
                acc[r][j].y = fmaf(xv[r].y, pv[j].y, acc[r][j].y);
                acc[r][j].z = fmaf(xv[r].z, pv[j].z, acc[r][j].z);
                acc[r][j].w = fmaf(xv[r].w, pv[j].w, acc[r][j].w);
            }
    }

    #pragma unroll
    for (int r = 0; r < 4; ++r) {
        int rowL = rg * 4 + r;
        #pragma unroll
        for (int j = 0; j < 4; ++j) {
            float s = (acc[r][j].x + acc[r][j].y) + (acc[r][j].z + acc[r][j].w);
            w0[rowL * 32 + cg * 4 + j] = sigmoidf_(mr[r] * s * INV_SCALE);
        }
    }
    __syncthreads();

    // hidden layer: w1[row][k] = sigmoid(sum_j w0[row][j]*hd[j][k] / scale)
    {
        const int k = tid & 31, g = tid >> 5;     // 8 row-slots
        #pragma unroll 2
        for (int r2 = 0; r2 < 16; ++r2) {
            int row = g + (r2 << 3);              // 0..127
            float s = 0.f;
            #pragma unroll
            for (int j = 0; j < 32; ++j)
                s = fmaf(w0[row * 32 + j], hd[j * 32 + k], s);
            w1[row * 33 + k] = sigmoidf_(s * INV_SCALE);
        }
    }
    __syncthreads();

    // evaluator: v[row] = sigmoid(sum_k w1[row][k]*ev[k] / scale)
    if (tid < 128) {
        float s = 0.f;
        #pragma unroll
        for (int k = 0; k < 32; ++k)
            s = fmaf(w1[tid * 33 + k], ev[k], s);
        v[rowBase + tid] = sigmoidf_(s * INV_SCALE);
    }
}

// ---- per-b softmax stats + in-place coefficient write: one block per b ----
// coeff[b,s] = m * exp(v-M) / (DM + 1e-12*Z), overwrites v (block owns its b)
__global__ __launch_bounds__(256) void kCoeff(
        float* __restrict__ v, const int* __restrict__ mask) {
    const int b = blockIdx.x, tid = threadIdx.x;
    __shared__ float sr[8];
    __shared__ float sM;

    float vv[8], mm[8];
    #pragma unroll
    for (int i = 0; i < 8; ++i) {
        int idx = b * S_ + i * 256 + tid;
        vv[i] = v[idx];
        mm[i] = (mask[idx] != 0) ? 1.0f : 0.0f;
    }
    float mx = vv[0];
    #pragma unroll
    for (int i = 1; i < 8; ++i) mx = fmaxf(mx, vv[i]);
    #pragma unroll
    for (int o = 32; o > 0; o >>= 1) mx = fmaxf(mx, __shfl_down(mx, o));
    if ((tid & 63) == 0) sr[tid >> 6] = mx;
    __syncthreads();
    if (tid == 0)
        sM = fmaxf(fmaxf(sr[0], sr[1]), fmaxf(sr[2], sr[3]));
    __syncthreads();
    const float M = sM;

    float z = 0.f, dm = 0.f;
    float ee[8];
    #pragma unroll
    for (int i = 0; i < 8; ++i) {
        ee[i] = __expf(vv[i] - M);
        z += ee[i];
        dm = fmaf(mm[i], ee[i], dm);
    }
    #pragma unroll
    for (int o = 32; o > 0; o >>= 1) {
        z  += __shfl_down(z, o);
        dm += __shfl_down(dm, o);
    }
    if ((tid & 63) == 0) { sr[tid >> 6] = z; sr[4 + (tid >> 6)] = dm; }
    __syncthreads();
    float Z  = (sr[0] + sr[1]) + (sr[2] + sr[3]);
    float DM = (sr[4] + sr[5]) + (sr[6] + sr[7]);
    float invDen = 1.0f / (DM + 1e-12f * Z);
    #pragma unroll
    for (int i = 0; i < 8; ++i) {
        int idx = b * S_ + i * 256 + tid;
        v[idx] = mm[i] * ee[i] * invDen;
    }
}

// ---- weighted sum, direct to out: block = (b, 64-float d-chunk) ----
__global__ __launch_bounds__(256) void kOut(
        const float* __restrict__ inp, const float* __restrict__ coeff,
        float* __restrict__ out) {
    const int bx = blockIdx.x;
    const int b = bx >> 3, dc = bx & 7;          // dc: 16 float4 = 64 floats
    const int tid = threadIdx.x;
    const int row16 = tid >> 4, col = tid & 15;
    __shared__ float cw[S_];
    __shared__ float4 red[256];

    #pragma unroll
    for (int i = 0; i < 8; ++i)
        cw[tid + i * 256] = coeff[b * S_ + tid + i * 256];
    __syncthreads();

    const float4* xp = (const float4*)inp + (size_t)b * S_ * 128 + dc * 16 + col;
    float4 a0 = make_float4(0,0,0,0), a1 = a0, a2 = a0, a3 = a0;
    for (int s0 = 0; s0 < S_; s0 += 64) {
        int s = s0 + row16;
        float4 x0 = xp[(size_t)(s     ) * 128];
        float4 x1 = xp[(size_t)(s + 16) * 128];
        float4 x2 = xp[(size_t)(s + 32) * 128];
        float4 x3 = xp[(size_t)(s + 48) * 128];
        float c0 = cw[s], c1 = cw[s + 16], c2 = cw[s + 32], c3 = cw[s + 48];
        a0.x = fmaf(c0, x0.x, a0.x); a0.y = fmaf(c0, x0.y, a0.y);
        a0.z = fmaf(c0, x0.z, a0.z); a0.w = fmaf(c0, x0.w, a0.w);
        a1.x = fmaf(c1, x1.x, a1.x); a1.y = fmaf(c1, x1.y, a1.y);
        a1.z = fmaf(c1, x1.z, a1.z); a1.w = fmaf(c1, x1.w, a1.w);
        a2.x = fmaf(c2, x2.x, a2.x); a2.y = fmaf(c2, x2.y, a2.y);
        a2.z = fmaf(c2, x2.z, a2.z); a2.w = fmaf(c2, x2.w, a2.w);
        a3.x = fmaf(c3, x3.x, a3.x); a3.y = fmaf(c3, x3.y, a3.y);
        a3.z = fmaf(c3, x3.z, a3.z); a3.w = fmaf(c3, x3.w, a3.w);
    }
    float4 a;
    a.x = (a0.x + a1.x) + (a2.x + a3.x);
    a.y = (a0.y + a1.y) + (a2.y + a3.y);
    a.z = (a0.z + a1.z) + (a2.z + a3.z);
    a.w = (a0.w + a1.w) + (a2.w + a3.w);
    red[tid] = a;
    __syncthreads();

    #pragma unroll
    for (int h = 8; h >= 1; h >>= 1) {
        if (row16 < h) {
            float4 p = red[(row16 + h) * 16 + col];
            float4 q = red[tid];
            q.x += p.x; q.y += p.y; q.z += p.z; q.w += p.w;
            red[tid] = q;
        }
        __syncthreads();
    }
    if (tid < 16)
        ((float4*)out)[b * 128 + dc * 16 + tid] = red[tid];
}

extern "C" void kernel_launch(void* const* d_in, const int* in_sizes, int n_in,
                              void* d_out, int out_size, void* d_ws, size_t ws_size,
                              hipStream_t stream) {
    const float* inp  = (const float*)d_in[0];
    const int*   mask = (const int*)d_in[1];
    const float* proj = (const float*)d_in[2];
    const float* hid  = (const float*)d_in[3];   // [1][32][32]
    const float* ev   = (const float*)d_in[4];   // [32]
    float* out = (float*)d_out;
    float* ws  = (float*)d_ws;

    float* PT = ws + PT_OFF;
    float* v  = ws + V_OFF;

    kTranspose<<<64, 256, 0, stream>>>(proj, PT);
    kScores   <<<BS_ / 128, 256, 0, stream>>>(inp, mask, PT, hid, ev, v);
    kCoeff    <<<B_, 256, 0, stream>>>(v, mask);
    kOut      <<<B_ * 8, 256, 0, stream>>>(inp, v, out);
}